// Round 11
// baseline (46.602 us; speedup 1.0000x reference)
//
#include <hip/hip_runtime.h>

// Chamfer (bidirectional 1-NN mean of squared distances), two [16384,3] fp32 clouds.
// Round-11: register-pressure hypothesis. R7-R10 all sit at ~30us vs 7.3us matrix
// floor, invariant to occupancy/LDS-traffic changes -> scheduler serialization
// under VGPR cap from over-unrolled loops (R7: full unroll = 16 live d-tuples).
// This round: MINIMAL live set (~91 VGPR): 1 A-frag/wave, one B-pair of d-tuples,
// #pragma unroll 1, hand software-pipeline (prefetch next bf-pair before min3s),
// hoisted zero-C. __launch_bounds__(256,4) -> true 4 waves/SIMD, no spill possible.
//
// MFMA formulation (one v_mfma_f32_32x32x16_f16 per 32x32 distance tile):
//   x = xh + xl (split fp16). K slots:
//     0..2 A=-2a_hi B=b_hi | 3..5 A=-2a_hi B=b_lo | 6..8 A=-2a_lo B=b_hi
//     9,10 A={a2_hi,a2_lo} B={1,1} | 11,12 A={1,1} B={b2_hi,b2_lo} | 13..15 zero
//   => D[i][j] = a2 + b2 - 2 a.b + O(3e-3), fp32 accumulators. (absmax 0.0 since R7)

typedef _Float16 half8 __attribute__((ext_vector_type(8)));
typedef float floatx16 __attribute__((ext_vector_type(16)));

#define NPTS 16384
#define BLOCK 256
#define WAVES 4
#define TILE 32
#define APB (WAVES * TILE)            // 128 A-points per block
#define NBSPLIT 8
#define BSWEEP (NPTS / NBSPLIT)       // 2048 B-points per block
#define CHUNKB 512                    // B-points staged in LDS at a time
#define NSTAGE (BSWEEP / CHUNKB)      // 4
#define NPAIRS (CHUNKB / (2 * TILE))  // 8 B-pairs per stage

union H8 { _Float16 h[8]; uint4 u; };

// Pack both clouds into A-format and B-format fragments (32 B/point each),
// and initialize the partial-min array.
__global__ __launch_bounds__(256) void prep_kernel(
    const float* __restrict__ P0, const float* __restrict__ P1,
    uint4* __restrict__ Ap, uint4* __restrict__ Bp,
    unsigned* __restrict__ dmin_all)
{
    const int i = blockIdx.x * 256 + threadIdx.x;      // 0..2*NPTS-1
    dmin_all[i] = 0x7F7F7F7Fu;                         // 3.39e38 > any real distance

    const float* P = (i < NPTS) ? P0 : P1;
    const int k = (i < NPTS) ? i : i - NPTS;
    const float x = P[k * 3 + 0], y = P[k * 3 + 1], z = P[k * 3 + 2];
    const float q2 = x * x + y * y + z * z;

    const _Float16 xh = (_Float16)x; const float xl = x - (float)xh;
    const _Float16 yh = (_Float16)y; const float yl = y - (float)yh;
    const _Float16 zh = (_Float16)z; const float zl = z - (float)zh;
    const _Float16 qh = (_Float16)q2; const float ql = q2 - (float)qh;
    const _Float16 one = (_Float16)1.0f, zero = (_Float16)0.0f;

    H8 a0, a1, b0, b1;
    a0.h[0] = (_Float16)(-2.0f * (float)xh);
    a0.h[1] = (_Float16)(-2.0f * (float)yh);
    a0.h[2] = (_Float16)(-2.0f * (float)zh);
    a0.h[3] = a0.h[0]; a0.h[4] = a0.h[1]; a0.h[5] = a0.h[2];
    a0.h[6] = (_Float16)(-2.0f * xl);
    a0.h[7] = (_Float16)(-2.0f * yl);
    a1.h[0] = (_Float16)(-2.0f * zl);
    a1.h[1] = qh; a1.h[2] = (_Float16)ql;
    a1.h[3] = one; a1.h[4] = one;
    a1.h[5] = zero; a1.h[6] = zero; a1.h[7] = zero;

    b0.h[0] = xh; b0.h[1] = yh; b0.h[2] = zh;
    b0.h[3] = (_Float16)xl; b0.h[4] = (_Float16)yl; b0.h[5] = (_Float16)zl;
    b0.h[6] = xh; b0.h[7] = yh;
    b1.h[0] = zh; b1.h[1] = one; b1.h[2] = one;
    b1.h[3] = qh; b1.h[4] = (_Float16)ql;
    b1.h[5] = zero; b1.h[6] = zero; b1.h[7] = zero;

    Ap[(size_t)i * 2 + 0] = a0.u; Ap[(size_t)i * 2 + 1] = a1.u;
    Bp[(size_t)i * 2 + 0] = b0.u; Bp[(size_t)i * 2 + 1] = b1.u;
}

__global__ __launch_bounds__(BLOCK, 4) void chamfer_mfma(
    const uint4* __restrict__ Ap, const uint4* __restrict__ Bp,
    unsigned* __restrict__ dmin_all)
{
    __shared__ uint4 sB[2][CHUNKB];   // [half][pt]: contiguous 16B/lane reads

    const int tid  = threadIdx.x;
    const int lane = tid & 63;
    const int wid  = tid >> 6;
    const int half = lane >> 5;
    const int lj   = lane & 31;

    const int dir = blockIdx.z;
    const uint4* Arole = Ap + (size_t)dir * NPTS * 2;
    const uint4* Brole = Bp + (size_t)(1 - dir) * NPTS * 2;
    unsigned* dmin = dmin_all + dir * NPTS;

    const int arow0 = blockIdx.x * APB + wid * TILE;

    // One A fragment per wave, resident in 4 VGPRs.
    const half8 af = *reinterpret_cast<const half8*>(
        &Arole[((size_t)(arow0 + lj)) * 2 + half]);

    const floatx16 ZC = (floatx16)(0.0f);   // hoisted zero-C, one 16-reg tuple

    float rmin[16];
#pragma unroll
    for (int r = 0; r < 16; ++r) rmin[r] = 3.0e38f;

    const int bbase = blockIdx.y * BSWEEP;

    for (int s = 0; s < NSTAGE; ++s) {
        __syncthreads();
        // Stage CHUNKB B-points: global [pt][half] -> LDS [half][pt].
        const uint4* src = &Brole[(size_t)(bbase + s * CHUNKB) * 2];
#pragma unroll
        for (int v = tid; v < 2 * CHUNKB; v += BLOCK) {
            sB[v & 1][v >> 1] = src[v];
        }
        __syncthreads();

        const uint4* myB = &sB[half][0];
        // Hand software-pipeline, unroll 1: live set stays ~91 VGPR (no spill,
        // no scheduler serialization under the 128 cap).
        half8 bf0 = *reinterpret_cast<const half8*>(&myB[lj]);
        half8 bf1 = *reinterpret_cast<const half8*>(&myB[TILE + lj]);
#pragma unroll 1
        for (int q = 0; q < NPAIRS; ++q) {
            const floatx16 d0 = __builtin_amdgcn_mfma_f32_32x32x16_f16(af, bf0, ZC, 0, 0, 0);
            const floatx16 d1 = __builtin_amdgcn_mfma_f32_32x32x16_f16(af, bf1, ZC, 0, 0, 0);
            if (q < NPAIRS - 1) {   // prefetch next pair while MFMAs are in flight
                bf0 = *reinterpret_cast<const half8*>(&myB[(2 * q + 2) * TILE + lj]);
                bf1 = *reinterpret_cast<const half8*>(&myB[(2 * q + 3) * TILE + lj]);
            }
#pragma unroll
            for (int r = 0; r < 16; ++r)
                rmin[r] = fminf(fminf(d0[r], d1[r]), rmin[r]);   // v_min3_f32
        }
    }

    // Butterfly min over the 32 lanes sharing this row set, then merge.
#pragma unroll
    for (int r = 0; r < 16; ++r) {
        float v = rmin[r];
        v = fminf(v, __shfl_xor(v, 1, 32));
        v = fminf(v, __shfl_xor(v, 2, 32));
        v = fminf(v, __shfl_xor(v, 4, 32));
        v = fminf(v, __shfl_xor(v, 8, 32));
        v = fminf(v, __shfl_xor(v, 16, 32));
        rmin[r] = v;
    }
    if (lj == 0) {
#pragma unroll
        for (int r = 0; r < 16; ++r) {
            const int row = (r & 3) + 8 * (r >> 2) + 4 * half;
            atomicMin(&dmin[arow0 + row],
                      __float_as_uint(fmaxf(rmin[r], 0.0f)));
        }
    }
}

__global__ __launch_bounds__(1024) void chamfer_reduce_kernel(
    const unsigned* __restrict__ dmin_all, float* __restrict__ out)
{
    __shared__ double sdata[1024];
    double s = 0.0;
    for (int i = threadIdx.x; i < 2 * NPTS; i += 1024)
        s += (double)__uint_as_float(dmin_all[i]);
    sdata[threadIdx.x] = s;
    __syncthreads();
    for (int off = 512; off > 0; off >>= 1) {
        if (threadIdx.x < off) sdata[threadIdx.x] += sdata[threadIdx.x + off];
        __syncthreads();
    }
    if (threadIdx.x == 0) out[0] = (float)(sdata[0] / (double)NPTS);
}

extern "C" void kernel_launch(void* const* d_in, const int* in_sizes, int n_in,
                              void* d_out, int out_size, void* d_ws, size_t ws_size,
                              hipStream_t stream)
{
    const float* P0 = (const float*)d_in[0];
    const float* P1 = (const float*)d_in[1];
    float* out = (float*)d_out;

    unsigned* dmin = (unsigned*)d_ws;                                     // 128 KB
    uint4* Ap = (uint4*)((char*)d_ws + 2 * NPTS * sizeof(unsigned));      // 1 MB
    uint4* Bp = Ap + (size_t)2 * NPTS * 2;                                // 1 MB

    prep_kernel<<<(2 * NPTS) / 256, 256, 0, stream>>>(P0, P1, Ap, Bp, dmin);

    dim3 grid(NPTS / APB, NBSPLIT, 2);   // 128 x 8 x 2 = 2048 blocks
    chamfer_mfma<<<grid, BLOCK, 0, stream>>>(Ap, Bp, dmin);

    chamfer_reduce_kernel<<<1, 1024, 0, stream>>>(dmin, out);
}

// Round 12
// 45.965 us; speedup vs baseline: 1.0139x; 1.0139x over previous
//
#include <hip/hip_runtime.h>

// Chamfer (bidirectional 1-NN mean of squared distances), two [16384,3] fp32 clouds.
// Round-12: consumer-pipelined MFMA. R7-R11 invariant ~30us (vs 6.9us matrix floor)
// across occupancy/LDS/VGPR changes -> per-pair serialization: min3 block consumes
// the MFMA results issued immediately before it, so every wave eats full MFMA
// result latency (+ possible AGPR->VGPR moves) once per B-pair. Fix: 2-deep
// result pipeline (dA/dB named tuples, static indexing): issue MFMAs for pair k,
// then min3 pair k-1's results while k is in flight.
//
// MFMA formulation (one v_mfma_f32_32x32x16_f16 per 32x32 distance tile):
//   x = xh + xl (split fp16). K slots:
//     0..2 A=-2a_hi B=b_hi | 3..5 A=-2a_hi B=b_lo | 6..8 A=-2a_lo B=b_hi
//     9,10 A={a2_hi,a2_lo} B={1,1} | 11,12 A={1,1} B={b2_hi,b2_lo} | 13..15 zero
//   => D[i][j] = a2 + b2 - 2 a.b + O(3e-3), fp32 accumulators. (absmax 0.0 since R7)

typedef _Float16 half8 __attribute__((ext_vector_type(8)));
typedef float floatx16 __attribute__((ext_vector_type(16)));

#define NPTS 16384
#define BLOCK 256
#define WAVES 4
#define TILE 32
#define APB (WAVES * TILE)            // 128 A-points per block
#define NBSPLIT 8
#define BSWEEP (NPTS / NBSPLIT)       // 2048 B-points per block
#define CHUNKB 512                    // B-points staged in LDS at a time
#define NSTAGE (BSWEEP / CHUNKB)      // 4
#define NPAIRS (CHUNKB / (2 * TILE))  // 8 B-pairs per stage

union H8 { _Float16 h[8]; uint4 u; };

// Pack both clouds into A-format and B-format fragments (32 B/point each),
// and initialize the partial-min array.
__global__ __launch_bounds__(256) void prep_kernel(
    const float* __restrict__ P0, const float* __restrict__ P1,
    uint4* __restrict__ Ap, uint4* __restrict__ Bp,
    unsigned* __restrict__ dmin_all)
{
    const int i = blockIdx.x * 256 + threadIdx.x;      // 0..2*NPTS-1
    dmin_all[i] = 0x7F7F7F7Fu;                         // 3.39e38 > any real distance

    const float* P = (i < NPTS) ? P0 : P1;
    const int k = (i < NPTS) ? i : i - NPTS;
    const float x = P[k * 3 + 0], y = P[k * 3 + 1], z = P[k * 3 + 2];
    const float q2 = x * x + y * y + z * z;

    const _Float16 xh = (_Float16)x; const float xl = x - (float)xh;
    const _Float16 yh = (_Float16)y; const float yl = y - (float)yh;
    const _Float16 zh = (_Float16)z; const float zl = z - (float)zh;
    const _Float16 qh = (_Float16)q2; const float ql = q2 - (float)qh;
    const _Float16 one = (_Float16)1.0f, zero = (_Float16)0.0f;

    H8 a0, a1, b0, b1;
    a0.h[0] = (_Float16)(-2.0f * (float)xh);
    a0.h[1] = (_Float16)(-2.0f * (float)yh);
    a0.h[2] = (_Float16)(-2.0f * (float)zh);
    a0.h[3] = a0.h[0]; a0.h[4] = a0.h[1]; a0.h[5] = a0.h[2];
    a0.h[6] = (_Float16)(-2.0f * xl);
    a0.h[7] = (_Float16)(-2.0f * yl);
    a1.h[0] = (_Float16)(-2.0f * zl);
    a1.h[1] = qh; a1.h[2] = (_Float16)ql;
    a1.h[3] = one; a1.h[4] = one;
    a1.h[5] = zero; a1.h[6] = zero; a1.h[7] = zero;

    b0.h[0] = xh; b0.h[1] = yh; b0.h[2] = zh;
    b0.h[3] = (_Float16)xl; b0.h[4] = (_Float16)yl; b0.h[5] = (_Float16)zl;
    b0.h[6] = xh; b0.h[7] = yh;
    b1.h[0] = zh; b1.h[1] = one; b1.h[2] = one;
    b1.h[3] = qh; b1.h[4] = (_Float16)ql;
    b1.h[5] = zero; b1.h[6] = zero; b1.h[7] = zero;

    Ap[(size_t)i * 2 + 0] = a0.u; Ap[(size_t)i * 2 + 1] = a1.u;
    Bp[(size_t)i * 2 + 0] = b0.u; Bp[(size_t)i * 2 + 1] = b1.u;
}

#define MF(bf) __builtin_amdgcn_mfma_f32_32x32x16_f16(af, (bf), ZC, 0, 0, 0)
#define MIN3(d0, d1)                                            \
    _Pragma("unroll")                                           \
    for (int r = 0; r < 16; ++r)                                \
        rmin[r] = fminf(fminf((d0)[r], (d1)[r]), rmin[r]);

__global__ __launch_bounds__(BLOCK, 4) void chamfer_mfma(
    const uint4* __restrict__ Ap, const uint4* __restrict__ Bp,
    unsigned* __restrict__ dmin_all)
{
    __shared__ uint4 sB[2][CHUNKB];   // [half][pt]: contiguous 16B/lane reads

    const int tid  = threadIdx.x;
    const int lane = tid & 63;
    const int wid  = tid >> 6;
    const int half = lane >> 5;
    const int lj   = lane & 31;

    const int dir = blockIdx.z;
    const uint4* Arole = Ap + (size_t)dir * NPTS * 2;
    const uint4* Brole = Bp + (size_t)(1 - dir) * NPTS * 2;
    unsigned* dmin = dmin_all + dir * NPTS;

    const int arow0 = blockIdx.x * APB + wid * TILE;

    // One A fragment per wave, resident in 4 VGPRs.
    const half8 af = *reinterpret_cast<const half8*>(
        &Arole[((size_t)(arow0 + lj)) * 2 + half]);

    const floatx16 ZC = (floatx16)(0.0f);   // hoisted zero-C

    float rmin[16];
#pragma unroll
    for (int r = 0; r < 16; ++r) rmin[r] = 3.0e38f;

    const int bbase = blockIdx.y * BSWEEP;

    for (int s = 0; s < NSTAGE; ++s) {
        __syncthreads();
        // Stage CHUNKB B-points: global [pt][half] -> LDS [half][pt].
        const uint4* src = &Brole[(size_t)(bbase + s * CHUNKB) * 2];
#pragma unroll
        for (int v = tid; v < 2 * CHUNKB; v += BLOCK) {
            sB[v & 1][v >> 1] = src[v];
        }
        __syncthreads();

        const uint4* myB = &sB[half][0];

        // 2-deep consumer pipeline over NPAIRS=8 B-pairs. While pair k's MFMAs
        // are in flight, min3 consumes pair k-1's results (independent data).
        half8 x0 = *reinterpret_cast<const half8*>(&myB[0 * TILE + lj]);
        half8 x1 = *reinterpret_cast<const half8*>(&myB[1 * TILE + lj]);
        floatx16 dA0 = MF(x0);
        floatx16 dA1 = MF(x1);
#pragma unroll 1
        for (int k = 1; k + 1 < NPAIRS; k += 2) {
            const half8 y0 = *reinterpret_cast<const half8*>(&myB[(2 * k + 0) * TILE + lj]);
            const half8 y1 = *reinterpret_cast<const half8*>(&myB[(2 * k + 1) * TILE + lj]);
            const floatx16 dB0 = MF(y0);
            const floatx16 dB1 = MF(y1);
            MIN3(dA0, dA1);                 // consume pair k-1 under pair k's latency
            x0 = *reinterpret_cast<const half8*>(&myB[(2 * k + 2) * TILE + lj]);
            x1 = *reinterpret_cast<const half8*>(&myB[(2 * k + 3) * TILE + lj]);
            dA0 = MF(x0);
            dA1 = MF(x1);
            MIN3(dB0, dB1);                 // consume pair k under pair k+1's latency
        }
        {   // epilogue: pair NPAIRS-1 (k=7), then drain both
            const half8 y0 = *reinterpret_cast<const half8*>(&myB[(2 * (NPAIRS - 1) + 0) * TILE + lj]);
            const half8 y1 = *reinterpret_cast<const half8*>(&myB[(2 * (NPAIRS - 1) + 1) * TILE + lj]);
            const floatx16 dB0 = MF(y0);
            const floatx16 dB1 = MF(y1);
            MIN3(dA0, dA1);
            MIN3(dB0, dB1);
        }
    }

    // Butterfly min over the 32 lanes sharing this row set, then merge.
#pragma unroll
    for (int r = 0; r < 16; ++r) {
        float v = rmin[r];
        v = fminf(v, __shfl_xor(v, 1, 32));
        v = fminf(v, __shfl_xor(v, 2, 32));
        v = fminf(v, __shfl_xor(v, 4, 32));
        v = fminf(v, __shfl_xor(v, 8, 32));
        v = fminf(v, __shfl_xor(v, 16, 32));
        rmin[r] = v;
    }
    if (lj == 0) {
#pragma unroll
        for (int r = 0; r < 16; ++r) {
            const int row = (r & 3) + 8 * (r >> 2) + 4 * half;
            atomicMin(&dmin[arow0 + row],
                      __float_as_uint(fmaxf(rmin[r], 0.0f)));
        }
    }
}

__global__ __launch_bounds__(1024) void chamfer_reduce_kernel(
    const unsigned* __restrict__ dmin_all, float* __restrict__ out)
{
    __shared__ double sdata[1024];
    double s = 0.0;
    for (int i = threadIdx.x; i < 2 * NPTS; i += 1024)
        s += (double)__uint_as_float(dmin_all[i]);
    sdata[threadIdx.x] = s;
    __syncthreads();
    for (int off = 512; off > 0; off >>= 1) {
        if (threadIdx.x < off) sdata[threadIdx.x] += sdata[threadIdx.x + off];
        __syncthreads();
    }
    if (threadIdx.x == 0) out[0] = (float)(sdata[0] / (double)NPTS);
}

extern "C" void kernel_launch(void* const* d_in, const int* in_sizes, int n_in,
                              void* d_out, int out_size, void* d_ws, size_t ws_size,
                              hipStream_t stream)
{
    const float* P0 = (const float*)d_in[0];
    const float* P1 = (const float*)d_in[1];
    float* out = (float*)d_out;

    unsigned* dmin = (unsigned*)d_ws;                                     // 128 KB
    uint4* Ap = (uint4*)((char*)d_ws + 2 * NPTS * sizeof(unsigned));      // 1 MB
    uint4* Bp = Ap + (size_t)2 * NPTS * 2;                                // 1 MB

    prep_kernel<<<(2 * NPTS) / 256, 256, 0, stream>>>(P0, P1, Ap, Bp, dmin);

    dim3 grid(NPTS / APB, NBSPLIT, 2);   // 128 x 8 x 2 = 2048 blocks
    chamfer_mfma<<<grid, BLOCK, 0, stream>>>(Ap, Bp, dmin);

    chamfer_reduce_kernel<<<1, 1024, 0, stream>>>(dmin, out);
}

// Round 13
// 44.286 us; speedup vs baseline: 1.0523x; 1.0379x over previous
//
#include <hip/hip_runtime.h>

// Chamfer (bidirectional 1-NN mean of squared distances), two [16384,3] fp32 clouds.
// Round-13: BARRIER-FREE structure. R7-R12 invariant ~30us (573 TF-equiv) matches
// the known ceiling of 2-phase stage->barrier->compute MFMA structures (learn_hip
// m233: ~600 TF; the s_waitcnt vmcnt(0) lgkmcnt(0) drain before each s_barrier
// stalls all waves together). Fix: B operands (1 MB, L2/L3-resident) are read
// DIRECTLY from global in the inner loop -- no LDS, no __syncthreads, no drains.
// Each wave's 64x16B fragment load covers one contiguous 1KB block (coalesced).
// 2 A-frags/wave so each B-fragment load feeds 2 MFMAs (halves load traffic).
//
// MFMA formulation (one v_mfma_f32_32x32x16_f16 per 32x32 distance tile):
//   x = xh + xl (split fp16). K slots:
//     0..2 A=-2a_hi B=b_hi | 3..5 A=-2a_hi B=b_lo | 6..8 A=-2a_lo B=b_hi
//     9,10 A={a2_hi,a2_lo} B={1,1} | 11,12 A={1,1} B={b2_hi,b2_lo} | 13..15 zero
//   => D[i][j] = a2 + b2 - 2 a.b + O(3e-3), fp32 accumulators. (absmax 0.0 since R7)

typedef _Float16 half8 __attribute__((ext_vector_type(8)));
typedef float floatx16 __attribute__((ext_vector_type(16)));

#define NPTS 16384
#define BLOCK 256
#define WAVES 4
#define TILE 32
#define ROWSW (2 * TILE)              // 64 A-rows per wave (2 fragments)
#define APB (WAVES * ROWSW)           // 256 A-points per block
#define NBSPLIT 8
#define BSWEEP (NPTS / NBSPLIT)       // 2048 B-points per block
#define BPAIRS (BSWEEP / (2 * TILE))  // 32 B-pairs per block

union H8 { _Float16 h[8]; uint4 u; };

// Pack both clouds into A-format and B-format fragments (32 B/point each),
// and initialize the partial-min array.
__global__ __launch_bounds__(256) void prep_kernel(
    const float* __restrict__ P0, const float* __restrict__ P1,
    uint4* __restrict__ Ap, uint4* __restrict__ Bp,
    unsigned* __restrict__ dmin_all)
{
    const int i = blockIdx.x * 256 + threadIdx.x;      // 0..2*NPTS-1
    dmin_all[i] = 0x7F7F7F7Fu;                         // 3.39e38 > any real distance

    const float* P = (i < NPTS) ? P0 : P1;
    const int k = (i < NPTS) ? i : i - NPTS;
    const float x = P[k * 3 + 0], y = P[k * 3 + 1], z = P[k * 3 + 2];
    const float q2 = x * x + y * y + z * z;

    const _Float16 xh = (_Float16)x; const float xl = x - (float)xh;
    const _Float16 yh = (_Float16)y; const float yl = y - (float)yh;
    const _Float16 zh = (_Float16)z; const float zl = z - (float)zh;
    const _Float16 qh = (_Float16)q2; const float ql = q2 - (float)qh;
    const _Float16 one = (_Float16)1.0f, zero = (_Float16)0.0f;

    H8 a0, a1, b0, b1;
    a0.h[0] = (_Float16)(-2.0f * (float)xh);
    a0.h[1] = (_Float16)(-2.0f * (float)yh);
    a0.h[2] = (_Float16)(-2.0f * (float)zh);
    a0.h[3] = a0.h[0]; a0.h[4] = a0.h[1]; a0.h[5] = a0.h[2];
    a0.h[6] = (_Float16)(-2.0f * xl);
    a0.h[7] = (_Float16)(-2.0f * yl);
    a1.h[0] = (_Float16)(-2.0f * zl);
    a1.h[1] = qh; a1.h[2] = (_Float16)ql;
    a1.h[3] = one; a1.h[4] = one;
    a1.h[5] = zero; a1.h[6] = zero; a1.h[7] = zero;

    b0.h[0] = xh; b0.h[1] = yh; b0.h[2] = zh;
    b0.h[3] = (_Float16)xl; b0.h[4] = (_Float16)yl; b0.h[5] = (_Float16)zl;
    b0.h[6] = xh; b0.h[7] = yh;
    b1.h[0] = zh; b1.h[1] = one; b1.h[2] = one;
    b1.h[3] = qh; b1.h[4] = (_Float16)ql;
    b1.h[5] = zero; b1.h[6] = zero; b1.h[7] = zero;

    Ap[(size_t)i * 2 + 0] = a0.u; Ap[(size_t)i * 2 + 1] = a1.u;
    Bp[(size_t)i * 2 + 0] = b0.u; Bp[(size_t)i * 2 + 1] = b1.u;
}

#define MF(afx, bf) __builtin_amdgcn_mfma_f32_32x32x16_f16((afx), (bf), ZC, 0, 0, 0)
#define MIN3(rm, d0, d1)                                        \
    _Pragma("unroll")                                           \
    for (int r = 0; r < 16; ++r)                                \
        (rm)[r] = fminf(fminf((d0)[r], (d1)[r]), (rm)[r]);

__global__ __launch_bounds__(BLOCK, 4) void chamfer_mfma(
    const uint4* __restrict__ Ap, const uint4* __restrict__ Bp,
    unsigned* __restrict__ dmin_all)
{
    const int tid  = threadIdx.x;
    const int lane = tid & 63;
    const int wid  = tid >> 6;
    const int half = lane >> 5;
    const int lj   = lane & 31;

    const int dir = blockIdx.z;
    const uint4* Arole = Ap + (size_t)dir * NPTS * 2;
    const uint4* Brole = Bp + (size_t)(1 - dir) * NPTS * 2;
    unsigned* dmin = dmin_all + dir * NPTS;

    const int arow0 = blockIdx.x * APB + wid * ROWSW;

    // Two A fragments per wave (rows arow0+lj, arow0+32+lj), resident in 8 VGPRs.
    const half8 af0 = *reinterpret_cast<const half8*>(
        &Arole[((size_t)(arow0 + lj)) * 2 + half]);
    const half8 af1 = *reinterpret_cast<const half8*>(
        &Arole[((size_t)(arow0 + 32 + lj)) * 2 + half]);

    const floatx16 ZC = (floatx16)(0.0f);   // hoisted zero-C

    float rmin0[16], rmin1[16];
#pragma unroll
    for (int r = 0; r < 16; ++r) { rmin0[r] = 3.0e38f; rmin1[r] = 3.0e38f; }

    // B fragments read directly from global (L2-resident 1MB). Wave reads one
    // contiguous 1KB block per fragment (lane-permuted, fully coalesced).
    // No LDS, no barriers: waves free-run; 4 waves/SIMD hide L2 latency.
    const uint4* Bc = Brole + (size_t)(blockIdx.y * BSWEEP) * 2;
#pragma unroll 2
    for (int q = 0; q < BPAIRS; ++q) {
        const half8 bf0 = *reinterpret_cast<const half8*>(
            &Bc[(size_t)((2 * q + 0) * TILE + lj) * 2 + half]);
        const half8 bf1 = *reinterpret_cast<const half8*>(
            &Bc[(size_t)((2 * q + 1) * TILE + lj) * 2 + half]);
        floatx16 d0 = MF(af0, bf0);
        floatx16 d1 = MF(af0, bf1);
        MIN3(rmin0, d0, d1);
        d0 = MF(af1, bf0);
        d1 = MF(af1, bf1);
        MIN3(rmin1, d0, d1);
    }

    // Butterfly min over the 32 lanes sharing each row set, then merge.
#pragma unroll
    for (int r = 0; r < 16; ++r) {
        float v0 = rmin0[r];
        v0 = fminf(v0, __shfl_xor(v0, 1, 32));
        v0 = fminf(v0, __shfl_xor(v0, 2, 32));
        v0 = fminf(v0, __shfl_xor(v0, 4, 32));
        v0 = fminf(v0, __shfl_xor(v0, 8, 32));
        v0 = fminf(v0, __shfl_xor(v0, 16, 32));
        rmin0[r] = v0;
        float v1 = rmin1[r];
        v1 = fminf(v1, __shfl_xor(v1, 1, 32));
        v1 = fminf(v1, __shfl_xor(v1, 2, 32));
        v1 = fminf(v1, __shfl_xor(v1, 4, 32));
        v1 = fminf(v1, __shfl_xor(v1, 8, 32));
        v1 = fminf(v1, __shfl_xor(v1, 16, 32));
        rmin1[r] = v1;
    }
    if (lj == 0) {
#pragma unroll
        for (int r = 0; r < 16; ++r) {
            const int row = (r & 3) + 8 * (r >> 2) + 4 * half;
            atomicMin(&dmin[arow0 + row],
                      __float_as_uint(fmaxf(rmin0[r], 0.0f)));
            atomicMin(&dmin[arow0 + 32 + row],
                      __float_as_uint(fmaxf(rmin1[r], 0.0f)));
        }
    }
}

__global__ __launch_bounds__(1024) void chamfer_reduce_kernel(
    const unsigned* __restrict__ dmin_all, float* __restrict__ out)
{
    __shared__ double sdata[1024];
    double s = 0.0;
    for (int i = threadIdx.x; i < 2 * NPTS; i += 1024)
        s += (double)__uint_as_float(dmin_all[i]);
    sdata[threadIdx.x] = s;
    __syncthreads();
    for (int off = 512; off > 0; off >>= 1) {
        if (threadIdx.x < off) sdata[threadIdx.x] += sdata[threadIdx.x + off];
        __syncthreads();
    }
    if (threadIdx.x == 0) out[0] = (float)(sdata[0] / (double)NPTS);
}

extern "C" void kernel_launch(void* const* d_in, const int* in_sizes, int n_in,
                              void* d_out, int out_size, void* d_ws, size_t ws_size,
                              hipStream_t stream)
{
    const float* P0 = (const float*)d_in[0];
    const float* P1 = (const float*)d_in[1];
    float* out = (float*)d_out;

    unsigned* dmin = (unsigned*)d_ws;                                     // 128 KB
    uint4* Ap = (uint4*)((char*)d_ws + 2 * NPTS * sizeof(unsigned));      // 1 MB
    uint4* Bp = Ap + (size_t)2 * NPTS * 2;                                // 1 MB

    prep_kernel<<<(2 * NPTS) / 256, 256, 0, stream>>>(P0, P1, Ap, Bp, dmin);

    dim3 grid(NPTS / APB, NBSPLIT, 2);   // 64 x 8 x 2 = 1024 blocks, 4 blocks/CU
    chamfer_mfma<<<grid, BLOCK, 0, stream>>>(Ap, Bp, dmin);

    chamfer_reduce_kernel<<<1, 1024, 0, stream>>>(dmin, out);
}